// Round 1
// baseline (49131.549 us; speedup 1.0000x reference)
//
#include <hip/hip_runtime.h>
#include <math.h>

// Problem constants
#define DD   512
#define HH   8
#define DHH  64
#define LL   8
#define FF   2048
#define NMEL 80
#define BB   8
#define SS   1024
#define MM   (BB*SS)   // 8192 rows

// ---------------------------------------------------------------------------
// proj + positional encoding: h = mel @ proj_w + proj_b + pe
// one block per row (b,s); mel row (80) staged in LDS
// ---------------------------------------------------------------------------
__global__ __launch_bounds__(256) void proj_pe_kernel(
    const float* __restrict__ mel, const float* __restrict__ pw,
    const float* __restrict__ pb, const float* __restrict__ pe,
    float* __restrict__ h)
{
    int row = blockIdx.x;            // 0..8191
    int s = row & (SS - 1);
    __shared__ float m_s[NMEL];
    int t = threadIdx.x;
    if (t < NMEL) m_s[t] = mel[(size_t)row * NMEL + t];
    __syncthreads();
    for (int d = t; d < DD; d += 256) {
        float acc = pb[d] + pe[(size_t)s * DD + d];
        #pragma unroll 8
        for (int k = 0; k < NMEL; ++k)
            acc = fmaf(m_s[k], pw[(size_t)k * DD + d], acc);
        h[(size_t)row * DD + d] = acc;
    }
}

// ---------------------------------------------------------------------------
// LayerNorm over last dim (512). One block (256 threads) per row.
// ---------------------------------------------------------------------------
__global__ __launch_bounds__(256) void ln_kernel(
    const float* __restrict__ in, const float* __restrict__ g,
    const float* __restrict__ bta, float* __restrict__ out)
{
    int row = blockIdx.x;
    const float* xr = in + (size_t)row * DD;
    int t = threadIdx.x;
    float x0 = xr[t], x1 = xr[t + 256];
    float s = x0 + x1;
    float ss = x0 * x0 + x1 * x1;
    #pragma unroll
    for (int off = 32; off; off >>= 1) {
        s  += __shfl_down(s, off);
        ss += __shfl_down(ss, off);
    }
    __shared__ float red1[4], red2[4];
    int lane = t & 63, w = t >> 6;
    if (lane == 0) { red1[w] = s; red2[w] = ss; }
    __syncthreads();
    s  = red1[0] + red1[1] + red1[2] + red1[3];
    ss = red2[0] + red2[1] + red2[2] + red2[3];
    float mu  = s * (1.f / DD);
    float var = ss * (1.f / DD) - mu * mu;
    float rstd = rsqrtf(var + 1e-5f);
    out[(size_t)row * DD + t]       = (x0 - mu) * rstd * g[t]       + bta[t];
    out[(size_t)row * DD + t + 256] = (x1 - mu) * rstd * g[t + 256] + bta[t + 256];
}

// ---------------------------------------------------------------------------
// Tiled fp32 GEMM: C[M,N] = A[M,K] @ W[K,N] (+bias) (+GELU) (+resid)
// BM=BN=64, BK=16, 256 threads, 4x4 per thread.
// A_HEADS: gather A from (B,H,S,DH) layout (attention ctx -> o-proj)
// C_HEADS: scatter C to (B,H,S,DH) layout (QKV projections)
// M must be a multiple of 64; N handled with bounds checks.
// ---------------------------------------------------------------------------
template<bool A_HEADS, bool C_HEADS, bool GELU_EP, bool RESID>
__global__ __launch_bounds__(256) void gemm_f32(
    const float* __restrict__ A, const float* __restrict__ W,
    const float* __restrict__ bias, const float* __restrict__ resid,
    float* __restrict__ C, int M, int N, int K)
{
    __shared__ float As[16][64 + 1];
    __shared__ float Bs[16][64];
    int bm = blockIdx.y * 64;
    int bn = blockIdx.x * 64;
    int t = threadIdx.x;
    int tx = t & 15, ty = t >> 4;
    float acc[4][4] = {};

    for (int k0 = 0; k0 < K; k0 += 16) {
        #pragma unroll
        for (int i = 0; i < 4; ++i) {
            int idx = t + i * 256;
            int r = idx >> 4, c = idx & 15;
            int m = bm + r, k = k0 + c;
            float v;
            if (A_HEADS) {
                int b = m >> 10, sIdx = m & (SS - 1), hh = k >> 6, d = k & 63;
                v = A[((size_t)(b * HH + hh) << 16) + (sIdx << 6) + d];
            } else {
                v = A[(size_t)m * K + k];
            }
            As[c][r] = v;
        }
        #pragma unroll
        for (int i = 0; i < 4; ++i) {
            int idx = t + i * 256;
            int kk = idx >> 6, n = idx & 63;
            int gn = bn + n;
            Bs[kk][n] = (gn < N) ? W[(size_t)(k0 + kk) * N + gn] : 0.f;
        }
        __syncthreads();
        #pragma unroll
        for (int kk = 0; kk < 16; ++kk) {
            float a[4], b[4];
            #pragma unroll
            for (int i = 0; i < 4; ++i) a[i] = As[kk][ty * 4 + i];
            #pragma unroll
            for (int j = 0; j < 4; ++j) b[j] = Bs[kk][tx * 4 + j];
            #pragma unroll
            for (int i = 0; i < 4; ++i)
                #pragma unroll
                for (int j = 0; j < 4; ++j)
                    acc[i][j] = fmaf(a[i], b[j], acc[i][j]);
        }
        __syncthreads();
    }

    #pragma unroll
    for (int i = 0; i < 4; ++i) {
        int m = bm + ty * 4 + i;
        #pragma unroll
        for (int j = 0; j < 4; ++j) {
            int n = bn + tx * 4 + j;
            if (n >= N) continue;
            float v = acc[i][j];
            if (bias) v += bias[n];
            if (GELU_EP) v = 0.5f * v * (1.f + erff(v * 0.70710678118654752440f));
            if (RESID) v += resid[(size_t)m * N + n];
            if (C_HEADS) {
                int b = m >> 10, sIdx = m & (SS - 1), hh = n >> 6, d = n & 63;
                C[((size_t)(b * HH + hh) << 16) + (sIdx << 6) + d] = v;
            } else {
                C[(size_t)m * N + n] = v;
            }
        }
    }
}

// ---------------------------------------------------------------------------
// Attention: one block per (b,h,query). q,k,v,ctx are (B,H,S,DH).
// scores in LDS, block softmax, coalesced PV.
// ---------------------------------------------------------------------------
__global__ __launch_bounds__(256) void attn_kernel(
    const float* __restrict__ q, const float* __restrict__ k,
    const float* __restrict__ v, float* __restrict__ ctx)
{
    int gid = blockIdx.x;                 // 0 .. B*H*S-1
    int s = gid & (SS - 1);
    int bh = gid >> 10;                   // 0..63
    const float* qrow  = q + ((size_t)bh << 16) + (s << 6);
    const float* kbase = k + ((size_t)bh << 16);
    const float* vbase = v + ((size_t)bh << 16);

    __shared__ float qs[DHH];
    __shared__ float sc[SS];
    __shared__ float red[4];
    __shared__ float pv[4][DHH];

    int t = threadIdx.x;
    if (t < DHH) qs[t] = qrow[t];
    __syncthreads();

    const float scale = 0.125f;           // 1/sqrt(64)
    float lmax = -1e30f;
    for (int kk = t; kk < SS; kk += 256) {
        const float4* kr4 = reinterpret_cast<const float4*>(kbase + ((size_t)kk << 6));
        float dot = 0.f;
        #pragma unroll
        for (int d4 = 0; d4 < 16; ++d4) {
            float4 kv = kr4[d4];
            dot = fmaf(qs[d4 * 4 + 0], kv.x, dot);
            dot = fmaf(qs[d4 * 4 + 1], kv.y, dot);
            dot = fmaf(qs[d4 * 4 + 2], kv.z, dot);
            dot = fmaf(qs[d4 * 4 + 3], kv.w, dot);
        }
        dot *= scale;
        sc[kk] = dot;
        lmax = fmaxf(lmax, dot);
    }
    #pragma unroll
    for (int off = 32; off; off >>= 1) lmax = fmaxf(lmax, __shfl_down(lmax, off));
    int lane = t & 63, w = t >> 6;
    if (lane == 0) red[w] = lmax;
    __syncthreads();
    float mx = fmaxf(fmaxf(red[0], red[1]), fmaxf(red[2], red[3]));
    __syncthreads();

    float lsum = 0.f;
    for (int kk = t; kk < SS; kk += 256) {
        float p = expf(sc[kk] - mx);
        sc[kk] = p;
        lsum += p;
    }
    #pragma unroll
    for (int off = 32; off; off >>= 1) lsum += __shfl_down(lsum, off);
    if (lane == 0) red[w] = lsum;
    __syncthreads();
    float inv = 1.f / (red[0] + red[1] + red[2] + red[3]);

    int d = t & 63, g = t >> 6;
    float acc = 0.f;
    for (int kk = g; kk < SS; kk += 4)
        acc = fmaf(sc[kk], vbase[((size_t)kk << 6) + d], acc);
    pv[g][d] = acc;
    __syncthreads();
    if (t < DHH) {
        float o = (pv[0][t] + pv[1][t] + pv[2][t] + pv[3][t]) * inv;
        ctx[((size_t)bh << 16) + (s << 6) + t] = o;
    }
}

// ---------------------------------------------------------------------------
// Mean pool over sequence: pooled[b,d] = mean_s hf[b,s,d]
// ---------------------------------------------------------------------------
__global__ __launch_bounds__(512) void pool_kernel(
    const float* __restrict__ hf, float* __restrict__ pooled)
{
    int b = blockIdx.x;
    int d = threadIdx.x;                 // 512
    float acc = 0.f;
    for (int s = 0; s < SS; ++s)
        acc += hf[((size_t)(b * SS + s)) * DD + d];
    pooled[b * DD + d] = acc * (1.f / SS);
}

// ---------------------------------------------------------------------------
// Small heads: lang(100), intent(50), emotion(8) from pooled
// out layout: [lang 8x100][int 8x50][emo 8x8][speech ...]
// ---------------------------------------------------------------------------
__global__ __launch_bounds__(256) void heads_kernel(
    const float* __restrict__ pooled,
    const float* __restrict__ lw, const float* __restrict__ lb,
    const float* __restrict__ iw, const float* __restrict__ ib,
    const float* __restrict__ ew, const float* __restrict__ eb,
    float* __restrict__ out)
{
    int b = blockIdx.x;
    __shared__ float ps[DD];
    int t = threadIdx.x;
    ps[t] = pooled[b * DD + t];
    ps[t + 256] = pooled[b * DD + t + 256];
    __syncthreads();
    if (t < 158) {
        const float* wptr; const float* bptr; float* optr; int n; int j;
        if (t < 100)      { j = t;       wptr = lw; bptr = lb; optr = out;        n = 100; }
        else if (t < 150) { j = t - 100; wptr = iw; bptr = ib; optr = out + 800;  n = 50;  }
        else              { j = t - 150; wptr = ew; bptr = eb; optr = out + 1200; n = 8;   }
        float acc = bptr[j];
        for (int k2 = 0; k2 < DD; ++k2)
            acc = fmaf(ps[k2], wptr[(size_t)k2 * n + j], acc);
        optr[b * n + j] = acc;
    }
}

// ---------------------------------------------------------------------------
extern "C" void kernel_launch(void* const* d_in, const int* in_sizes, int n_in,
                              void* d_out, int out_size, void* d_ws, size_t ws_size,
                              hipStream_t stream)
{
    const float* mel    = (const float*)d_in[0];
    const float* pe     = (const float*)d_in[1];
    const float* proj_w = (const float*)d_in[2];
    const float* proj_b = (const float*)d_in[3];
    const float* Wq     = (const float*)d_in[4];
    const float* bq     = (const float*)d_in[5];
    const float* Wk     = (const float*)d_in[6];
    const float* bk     = (const float*)d_in[7];
    const float* Wv     = (const float*)d_in[8];
    const float* bv     = (const float*)d_in[9];
    const float* Wo     = (const float*)d_in[10];
    const float* bo     = (const float*)d_in[11];
    const float* ln1_g  = (const float*)d_in[12];
    const float* ln1_b  = (const float*)d_in[13];
    const float* ln2_g  = (const float*)d_in[14];
    const float* ln2_b  = (const float*)d_in[15];
    const float* Wi     = (const float*)d_in[16];
    const float* bi     = (const float*)d_in[17];
    const float* Wf     = (const float*)d_in[18];
    const float* bf     = (const float*)d_in[19];
    const float* lnf_g  = (const float*)d_in[20];
    const float* lnf_b  = (const float*)d_in[21];
    const float* lang_w = (const float*)d_in[22];
    const float* lang_b = (const float*)d_in[23];
    const float* int_w  = (const float*)d_in[24];
    const float* int_b  = (const float*)d_in[25];
    const float* emo_w  = (const float*)d_in[26];
    const float* emo_b  = (const float*)d_in[27];
    const float* sp_w   = (const float*)d_in[28];
    const float* sp_b   = (const float*)d_in[29];

    float* out = (float*)d_out;

    // workspace layout (floats): each activation buffer 8192*512 = 4,194,304
    const size_t NA = (size_t)MM * DD;          // 4,194,304
    float* ws   = (float*)d_ws;
    float* hbuf = ws;                            // persistent residual stream
    float* xbuf = ws + NA;                       // LN output / final hf
    float* qbuf = ws + 2 * NA;                   // (B,H,S,DH)
    float* kbuf = ws + 3 * NA;
    float* vbuf = ws + 4 * NA;
    float* cbuf = ws + 5 * NA;                   // attention context (B,H,S,DH)
    float* tbuf = ws + 6 * NA;                   // FFN chunk 2048 x 2048
    float* pooled = ws + 6 * NA + (size_t)2048 * FF;   // 8*512
    // total: 6*4.19M + 4.19M + 4K floats ~= 117.5 MB

    proj_pe_kernel<<<MM, 256, 0, stream>>>(mel, proj_w, proj_b, pe, hbuf);

    dim3 g512(DD / 64, MM / 64);    // (8, 128)

    for (int l = 0; l < LL; ++l) {
        const float* wq = Wq + (size_t)l * DD * DD;
        const float* wk = Wk + (size_t)l * DD * DD;
        const float* wv = Wv + (size_t)l * DD * DD;
        const float* wo = Wo + (size_t)l * DD * DD;
        const float* wi = Wi + (size_t)l * DD * FF;
        const float* wf = Wf + (size_t)l * FF * DD;

        ln_kernel<<<MM, 256, 0, stream>>>(hbuf, ln1_g + l * DD, ln1_b + l * DD, xbuf);

        gemm_f32<false, true, false, false><<<g512, 256, 0, stream>>>(
            xbuf, wq, bq + l * DD, nullptr, qbuf, MM, DD, DD);
        gemm_f32<false, true, false, false><<<g512, 256, 0, stream>>>(
            xbuf, wk, bk + l * DD, nullptr, kbuf, MM, DD, DD);
        gemm_f32<false, true, false, false><<<g512, 256, 0, stream>>>(
            xbuf, wv, bv + l * DD, nullptr, vbuf, MM, DD, DD);

        attn_kernel<<<BB * HH * SS, 256, 0, stream>>>(qbuf, kbuf, vbuf, cbuf);

        // h = h + ctx @ Wo + bo   (A gathered from heads layout)
        gemm_f32<true, false, false, true><<<g512, 256, 0, stream>>>(
            cbuf, wo, bo + l * DD, hbuf, hbuf, MM, DD, DD);

        ln_kernel<<<MM, 256, 0, stream>>>(hbuf, ln2_g + l * DD, ln2_b + l * DD, xbuf);

        // FFN in 4 chunks of 2048 rows to bound workspace
        for (int c = 0; c < 4; ++c) {
            float* xr = xbuf + (size_t)c * 2048 * DD;
            float* hr = hbuf + (size_t)c * 2048 * DD;
            gemm_f32<false, false, true, false><<<dim3(FF / 64, 2048 / 64), 256, 0, stream>>>(
                xr, wi, bi + l * FF, nullptr, tbuf, 2048, FF, DD);
            gemm_f32<false, false, false, true><<<dim3(DD / 64, 2048 / 64), 256, 0, stream>>>(
                tbuf, wf, bf + l * DD, hr, hr, 2048, DD, FF);
        }
    }

    // final LN -> xbuf (hf)
    ln_kernel<<<MM, 256, 0, stream>>>(hbuf, lnf_g, lnf_b, xbuf);

    pool_kernel<<<BB, 512, 0, stream>>>(xbuf, pooled);

    heads_kernel<<<BB, 256, 0, stream>>>(pooled, lang_w, lang_b, int_w, int_b,
                                         emo_w, emo_b, out);

    // speech logits: (8192 x 1000) = hf @ sp_w + sp_b
    gemm_f32<false, false, false, false><<<dim3((1000 + 63) / 64, MM / 64), 256, 0, stream>>>(
        xbuf, sp_w, sp_b, nullptr, out + 1264, MM, 1000, DD);
}

// Round 2
// 2375.624 us; speedup vs baseline: 20.6815x; 20.6815x over previous
//
#include <hip/hip_runtime.h>
#include <hip/hip_bf16.h>
#include <math.h>

// Problem constants
#define DD   512
#define HH   8
#define DHH  64
#define LL   8
#define FF   2048
#define NMEL 80
#define BB   8
#define SS   1024
#define MM   (BB*SS)   // 8192 rows

typedef __attribute__((ext_vector_type(8))) short bf16x8;   // 8 bf16 = 4 VGPRs
typedef __attribute__((ext_vector_type(4))) float f32x4;    // MFMA C/D

#define GLOAD_LDS16(g, l) __builtin_amdgcn_global_load_lds( \
    (const __attribute__((address_space(1))) void*)(g),      \
    (__attribute__((address_space(3))) void*)(l), 16, 0, 0)

// ---------------------------------------------------------------------------
// proj + positional encoding (fp32, K=80 — tiny)
// ---------------------------------------------------------------------------
__global__ __launch_bounds__(256) void proj_pe_kernel(
    const float* __restrict__ mel, const float* __restrict__ pw,
    const float* __restrict__ pb, const float* __restrict__ pe,
    float* __restrict__ h)
{
    int row = blockIdx.x;
    int s = row & (SS - 1);
    __shared__ float m_s[NMEL];
    int t = threadIdx.x;
    if (t < NMEL) m_s[t] = mel[(size_t)row * NMEL + t];
    __syncthreads();
    for (int d = t; d < DD; d += 256) {
        float acc = pb[d] + pe[(size_t)s * DD + d];
        #pragma unroll 8
        for (int k = 0; k < NMEL; ++k)
            acc = fmaf(m_s[k], pw[(size_t)k * DD + d], acc);
        h[(size_t)row * DD + d] = acc;
    }
}

// ---------------------------------------------------------------------------
// LayerNorm (fp32 in -> bf16 out). One block (256 threads) per row.
// ---------------------------------------------------------------------------
__global__ __launch_bounds__(256) void ln_kernel(
    const float* __restrict__ in, const float* __restrict__ g,
    const float* __restrict__ bta, __hip_bfloat16* __restrict__ out)
{
    int row = blockIdx.x;
    const float* xr = in + (size_t)row * DD;
    int t = threadIdx.x;
    float x0 = xr[t], x1 = xr[t + 256];
    float s = x0 + x1;
    float ss = x0 * x0 + x1 * x1;
    #pragma unroll
    for (int off = 32; off; off >>= 1) {
        s  += __shfl_down(s, off);
        ss += __shfl_down(ss, off);
    }
    __shared__ float red1[4], red2[4];
    int lane = t & 63, w = t >> 6;
    if (lane == 0) { red1[w] = s; red2[w] = ss; }
    __syncthreads();
    s  = red1[0] + red1[1] + red1[2] + red1[3];
    ss = red2[0] + red2[1] + red2[2] + red2[3];
    float mu  = s * (1.f / DD);
    float var = ss * (1.f / DD) - mu * mu;
    float rstd = rsqrtf(var + 1e-5f);
    out[(size_t)row * DD + t]       = __float2bfloat16((x0 - mu) * rstd * g[t]       + bta[t]);
    out[(size_t)row * DD + t + 256] = __float2bfloat16((x1 - mu) * rstd * g[t + 256] + bta[t + 256]);
}

// ---------------------------------------------------------------------------
// Weight convert+transpose: in fp32 [K][N] -> out bf16 [Npad][K] (rows>=N zero)
// blockIdx.z = layer (strides K*N / Npad*K)
// ---------------------------------------------------------------------------
__global__ __launch_bounds__(256) void wconv_kernel(
    const float* __restrict__ in, __hip_bfloat16* __restrict__ out,
    int K, int N, int Npad)
{
    __shared__ float tile[32][33];
    size_t lin  = (size_t)blockIdx.z * K * N;
    size_t lout = (size_t)blockIdx.z * Npad * K;
    int tx = threadIdx.x & 31, ty = threadIdx.x >> 5;
    int n0 = blockIdx.x * 32, k0 = blockIdx.y * 32;
    #pragma unroll
    for (int i = 0; i < 32; i += 8) {
        int k = k0 + ty + i, n = n0 + tx;
        tile[ty + i][tx] = (n < N) ? in[lin + (size_t)k * N + n] : 0.f;
    }
    __syncthreads();
    #pragma unroll
    for (int i = 0; i < 32; i += 8) {
        int n = n0 + ty + i, k = k0 + tx;
        out[lout + (size_t)n * K + k] = __float2bfloat16(tile[tx][ty + i]);
    }
}

// ---------------------------------------------------------------------------
// bf16 MFMA GEMM: C[M,N] = A[M,K] @ Bt[N,K]^T  (+bias) (+GELU) (+resid)
// 128x128 tile, BK=64, 256 threads (4 waves 2x2), 4x4 16x16 frags per wave.
// OUTMODE: 0=f32 flat, 1=bf16 flat, 2=bf16 heads [B,H,S,DH], 3=bf16 headsT [B,H,DH,S]
// ---------------------------------------------------------------------------
template<int OUTMODE, bool GELU_EP, bool RESID>
__global__ __launch_bounds__(256) void gemm_bf16(
    const __hip_bfloat16* __restrict__ A,
    const __hip_bfloat16* __restrict__ Bt,
    const float* __restrict__ bias,
    const float* __restrict__ resid,
    float* __restrict__ Cf,
    __hip_bfloat16* __restrict__ Cb,
    int M, int N, int K)
{
    __shared__ __align__(16) __hip_bfloat16 As[128 * 64];
    __shared__ __align__(16) __hip_bfloat16 Bs[128 * 64];
    int t = threadIdx.x;
    int w = t >> 6, lane = t & 63, g = lane >> 4, li = lane & 15;
    int wm = w >> 1, wn = w & 1;
    size_t bm = (size_t)blockIdx.y * 128;
    size_t bn = (size_t)blockIdx.x * 128;

    const f32x4 vzero = {0.f, 0.f, 0.f, 0.f};
    f32x4 acc[4][4];
    #pragma unroll
    for (int i = 0; i < 4; ++i)
        #pragma unroll
        for (int j = 0; j < 4; ++j) acc[i][j] = vzero;

    for (int k0 = 0; k0 < K; k0 += 64) {
        #pragma unroll
        for (int i = 0; i < 4; ++i) {
            int c = i * 256 + t;
            int row = c >> 3, col = (c & 7) << 3;
            GLOAD_LDS16(A + (bm + row) * (size_t)K + k0 + col, As + (size_t)c * 8);
        }
        #pragma unroll
        for (int i = 0; i < 4; ++i) {
            int c = i * 256 + t;
            int row = c >> 3, col = (c & 7) << 3;
            GLOAD_LDS16(Bt + (bn + row) * (size_t)K + k0 + col, Bs + (size_t)c * 8);
        }
        __syncthreads();
        #pragma unroll
        for (int kk = 0; kk < 2; ++kk) {
            bf16x8 af[4], bfr[4];
            #pragma unroll
            for (int mi = 0; mi < 4; ++mi)
                af[mi] = *reinterpret_cast<const bf16x8*>(As + (wm * 64 + mi * 16 + li) * 64 + kk * 32 + g * 8);
            #pragma unroll
            for (int ni = 0; ni < 4; ++ni)
                bfr[ni] = *reinterpret_cast<const bf16x8*>(Bs + (wn * 64 + ni * 16 + li) * 64 + kk * 32 + g * 8);
            #pragma unroll
            for (int mi = 0; mi < 4; ++mi)
                #pragma unroll
                for (int ni = 0; ni < 4; ++ni)
                    acc[mi][ni] = __builtin_amdgcn_mfma_f32_16x16x32_bf16(af[mi], bfr[ni], acc[mi][ni], 0, 0, 0);
        }
        __syncthreads();
    }

    #pragma unroll
    for (int mi = 0; mi < 4; ++mi) {
        #pragma unroll
        for (int ni = 0; ni < 4; ++ni) {
            f32x4 v = acc[mi][ni];
            int coll = wn * 64 + ni * 16 + li;
            size_t col = bn + coll;
            if ((int)col >= N) continue;          // only hits for speech head (N=1000)
            float bv = bias[col];
            #pragma unroll
            for (int r = 0; r < 4; ++r) {
                size_t row = bm + wm * 64 + mi * 16 + g * 4 + r;
                float x = v[r] + bv;
                if (GELU_EP) x = 0.5f * x * (1.f + erff(x * 0.70710678118654752440f));
                if (RESID)   x += resid[row * (size_t)N + col];
                if (OUTMODE == 0) {
                    Cf[row * (size_t)N + col] = x;
                } else if (OUTMODE == 1) {
                    Cb[row * (size_t)N + col] = __float2bfloat16(x);
                } else if (OUTMODE == 2) {
                    // heads: [B,H,S,DH]; row=(b,s), col=(h,d); N==512
                    size_t b = row >> 10, s = row & (SS - 1);
                    size_t h = col >> 6,  d = col & 63;
                    Cb[((b * HH + h) << 16) + (s << 6) + d] = __float2bfloat16(x);
                } else {
                    // headsT: [B,H,DH,S]
                    size_t b = row >> 10, s = row & (SS - 1);
                    size_t h = col >> 6,  d = col & 63;
                    Cb[((b * HH + h) << 16) + (d << 10) + s] = __float2bfloat16(x);
                }
            }
        }
    }
}

// ---------------------------------------------------------------------------
// MFMA flash attention. Grid (S/128, B*H), 256 threads = 4 waves, each wave
// owns a 32-query tile. Q,K in [B,H,S,DH] bf16; V in [B,H,DH,S] bf16 (transposed).
// Online softmax in base-2 domain. ctx out: bf16 [B,S,D] flat (h*64+d cols).
// ---------------------------------------------------------------------------
__global__ __launch_bounds__(256) void attn_mfma(
    const __hip_bfloat16* __restrict__ qb,
    const __hip_bfloat16* __restrict__ kb,
    const __hip_bfloat16* __restrict__ vtb,
    __hip_bfloat16* __restrict__ ctx)
{
    __shared__ __align__(16) __hip_bfloat16 Plds[4][32][32];
    int t = threadIdx.x;
    int w = t >> 6, lane = t & 63, g = lane >> 4, li = lane & 15;
    int bh = blockIdx.y;
    int b = bh >> 3, h = bh & 7;
    int q0 = (blockIdx.x * 4 + w) * 32;

    const __hip_bfloat16* Qp = qb  + ((size_t)bh << 16);
    const __hip_bfloat16* Kp = kb  + ((size_t)bh << 16);
    const __hip_bfloat16* Vp = vtb + ((size_t)bh << 16);

    // Q fragments live in registers for the whole KV sweep
    bf16x8 qf[2][2];
    #pragma unroll
    for (int qt = 0; qt < 2; ++qt)
        #pragma unroll
        for (int kk = 0; kk < 2; ++kk)
            qf[qt][kk] = *reinterpret_cast<const bf16x8*>(
                Qp + (size_t)(q0 + qt * 16 + li) * DHH + kk * 32 + g * 8);

    const f32x4 vzero = {0.f, 0.f, 0.f, 0.f};
    f32x4 acc_o[2][4];
    float m_r[2][4], l_r[2][4];
    #pragma unroll
    for (int qt = 0; qt < 2; ++qt) {
        #pragma unroll
        for (int dt = 0; dt < 4; ++dt) acc_o[qt][dt] = vzero;
        #pragma unroll
        for (int r = 0; r < 4; ++r) { m_r[qt][r] = -1e30f; l_r[qt][r] = 0.f; }
    }

    const float csc = 0.125f * 1.44269504088896340736f;  // scale * log2(e)

    for (int ks0 = 0; ks0 < SS; ks0 += 32) {
        // ---- S = Q K^T (raw dots) ----
        f32x4 accs[2][2];
        #pragma unroll
        for (int qt = 0; qt < 2; ++qt)
            #pragma unroll
            for (int kt = 0; kt < 2; ++kt) accs[qt][kt] = vzero;
        #pragma unroll
        for (int kk = 0; kk < 2; ++kk) {
            bf16x8 kf[2];
            #pragma unroll
            for (int kt = 0; kt < 2; ++kt)
                kf[kt] = *reinterpret_cast<const bf16x8*>(
                    Kp + (size_t)(ks0 + kt * 16 + li) * DHH + kk * 32 + g * 8);
            #pragma unroll
            for (int qt = 0; qt < 2; ++qt)
                #pragma unroll
                for (int kt = 0; kt < 2; ++kt)
                    accs[qt][kt] = __builtin_amdgcn_mfma_f32_16x16x32_bf16(qf[qt][kk], kf[kt], accs[qt][kt], 0, 0, 0);
        }

        // ---- online softmax (base-2). C-layout: col(k)=li, row(q)=g*4+r ----
        float mnew[2][4];
        #pragma unroll
        for (int qt = 0; qt < 2; ++qt)
            #pragma unroll
            for (int r = 0; r < 4; ++r)
                mnew[qt][r] = fmaxf(accs[qt][0][r], accs[qt][1][r]) * csc;
        #pragma unroll
        for (int mask = 1; mask < 16; mask <<= 1)
            #pragma unroll
            for (int qt = 0; qt < 2; ++qt)
                #pragma unroll
                for (int r = 0; r < 4; ++r)
                    mnew[qt][r] = fmaxf(mnew[qt][r], __shfl_xor(mnew[qt][r], mask));

        float alpha[2][4], rs[2][4];
        #pragma unroll
        for (int qt = 0; qt < 2; ++qt)
            #pragma unroll
            for (int r = 0; r < 4; ++r) {
                float mn = fmaxf(m_r[qt][r], mnew[qt][r]);
                alpha[qt][r] = exp2f(m_r[qt][r] - mn);
                m_r[qt][r] = mn;
                rs[qt][r] = 0.f;
            }
        #pragma unroll
        for (int qt = 0; qt < 2; ++qt)
            #pragma unroll
            for (int kt = 0; kt < 2; ++kt)
                #pragma unroll
                for (int r = 0; r < 4; ++r) {
                    float p = exp2f(accs[qt][kt][r] * csc - m_r[qt][r]);
                    rs[qt][r] += p;
                    Plds[w][qt * 16 + g * 4 + r][kt * 16 + li] = __float2bfloat16(p);
                }
        #pragma unroll
        for (int mask = 1; mask < 16; mask <<= 1)
            #pragma unroll
            for (int qt = 0; qt < 2; ++qt)
                #pragma unroll
                for (int r = 0; r < 4; ++r)
                    rs[qt][r] += __shfl_xor(rs[qt][r], mask);
        #pragma unroll
        for (int qt = 0; qt < 2; ++qt)
            #pragma unroll
            for (int r = 0; r < 4; ++r)
                l_r[qt][r] = l_r[qt][r] * alpha[qt][r] + rs[qt][r];
        #pragma unroll
        for (int qt = 0; qt < 2; ++qt)
            #pragma unroll
            for (int dt = 0; dt < 4; ++dt)
                #pragma unroll
                for (int r = 0; r < 4; ++r)
                    acc_o[qt][dt][r] *= alpha[qt][r];

        __builtin_amdgcn_wave_barrier();   // order P writes vs reads (1-wave LDS, in-order HW)

        // ---- O += P V : A=P[16q x 32k] from LDS, B=V^T rows contiguous ----
        bf16x8 pf[2];
        #pragma unroll
        for (int qt = 0; qt < 2; ++qt)
            pf[qt] = *reinterpret_cast<const bf16x8*>(&Plds[w][qt * 16 + li][g * 8]);
        #pragma unroll
        for (int dt = 0; dt < 4; ++dt) {
            bf16x8 vf = *reinterpret_cast<const bf16x8*>(
                Vp + (size_t)(dt * 16 + li) * SS + ks0 + g * 8);
            #pragma unroll
            for (int qt = 0; qt < 2; ++qt)
                acc_o[qt][dt] = __builtin_amdgcn_mfma_f32_16x16x32_bf16(pf[qt], vf, acc_o[qt][dt], 0, 0, 0);
        }
        __builtin_amdgcn_wave_barrier();   // P reads done before next tile overwrites
    }

    // ---- write ctx[b][s][h*64+d] ----
    #pragma unroll
    for (int qt = 0; qt < 2; ++qt)
        #pragma unroll
        for (int dt = 0; dt < 4; ++dt)
            #pragma unroll
            for (int r = 0; r < 4; ++r) {
                int q = q0 + qt * 16 + g * 4 + r;
                int d = dt * 16 + li;
                float o = acc_o[qt][dt][r] / l_r[qt][r];
                ctx[((size_t)(b * SS + q)) * DD + h * DHH + d] = __float2bfloat16(o);
            }
}

// ---------------------------------------------------------------------------
// Mean pool (bf16 in, fp32 out)
// ---------------------------------------------------------------------------
__global__ __launch_bounds__(512) void pool_kernel(
    const __hip_bfloat16* __restrict__ hf, float* __restrict__ pooled)
{
    int b = blockIdx.x;
    int d = threadIdx.x;
    float acc = 0.f;
    for (int s = 0; s < SS; ++s)
        acc += __bfloat162float(hf[((size_t)(b * SS + s)) * DD + d]);
    pooled[b * DD + d] = acc * (1.f / SS);
}

// ---------------------------------------------------------------------------
// Small heads (fp32)
// ---------------------------------------------------------------------------
__global__ __launch_bounds__(256) void heads_kernel(
    const float* __restrict__ pooled,
    const float* __restrict__ lw, const float* __restrict__ lb,
    const float* __restrict__ iw, const float* __restrict__ ib,
    const float* __restrict__ ew, const float* __restrict__ eb,
    float* __restrict__ out)
{
    int b = blockIdx.x;
    __shared__ float ps[DD];
    int t = threadIdx.x;
    ps[t] = pooled[b * DD + t];
    ps[t + 256] = pooled[b * DD + t + 256];
    __syncthreads();
    if (t < 158) {
        const float* wptr; const float* bptr; float* optr; int n; int j;
        if (t < 100)      { j = t;       wptr = lw; bptr = lb; optr = out;        n = 100; }
        else if (t < 150) { j = t - 100; wptr = iw; bptr = ib; optr = out + 800;  n = 50;  }
        else              { j = t - 150; wptr = ew; bptr = eb; optr = out + 1200; n = 8;   }
        float acc = bptr[j];
        for (int k2 = 0; k2 < DD; ++k2)
            acc = fmaf(ps[k2], wptr[(size_t)k2 * n + j], acc);
        optr[b * n + j] = acc;
    }
}

// ---------------------------------------------------------------------------
extern "C" void kernel_launch(void* const* d_in, const int* in_sizes, int n_in,
                              void* d_out, int out_size, void* d_ws, size_t ws_size,
                              hipStream_t stream)
{
    const float* mel    = (const float*)d_in[0];
    const float* pe     = (const float*)d_in[1];
    const float* proj_w = (const float*)d_in[2];
    const float* proj_b = (const float*)d_in[3];
    const float* Wq     = (const float*)d_in[4];
    const float* bq     = (const float*)d_in[5];
    const float* Wk     = (const float*)d_in[6];
    const float* bk     = (const float*)d_in[7];
    const float* Wv     = (const float*)d_in[8];
    const float* bv     = (const float*)d_in[9];
    const float* Wo     = (const float*)d_in[10];
    const float* bo     = (const float*)d_in[11];
    const float* ln1_g  = (const float*)d_in[12];
    const float* ln1_b  = (const float*)d_in[13];
    const float* ln2_g  = (const float*)d_in[14];
    const float* ln2_b  = (const float*)d_in[15];
    const float* Wi     = (const float*)d_in[16];
    const float* bi     = (const float*)d_in[17];
    const float* Wf     = (const float*)d_in[18];
    const float* bf     = (const float*)d_in[19];
    const float* lnf_g  = (const float*)d_in[20];
    const float* lnf_b  = (const float*)d_in[21];
    const float* lang_w = (const float*)d_in[22];
    const float* lang_b = (const float*)d_in[23];
    const float* int_w  = (const float*)d_in[24];
    const float* int_b  = (const float*)d_in[25];
    const float* emo_w  = (const float*)d_in[26];
    const float* emo_b  = (const float*)d_in[27];
    const float* sp_w   = (const float*)d_in[28];
    const float* sp_b   = (const float*)d_in[29];

    float* out = (float*)d_out;
    char* wsb = (char*)d_ws;

    // ---- workspace layout (bytes) ----
    float* hbuf           = (float*)(wsb);                         // fp32 residual, 16 MB
    __hip_bfloat16* xb    = (__hip_bfloat16*)(wsb + (16ull << 20)); // LN out bf16, 8 MB
    __hip_bfloat16* qbuf  = (__hip_bfloat16*)(wsb + (24ull << 20)); // 8 MB
    __hip_bfloat16* kbuf  = (__hip_bfloat16*)(wsb + (32ull << 20)); // 8 MB
    __hip_bfloat16* vtb   = (__hip_bfloat16*)(wsb + (40ull << 20)); // 8 MB
    __hip_bfloat16* ctx   = (__hip_bfloat16*)(wsb + (48ull << 20)); // 8 MB
    __hip_bfloat16* gbuf  = (__hip_bfloat16*)(wsb + (24ull << 20)); // 32 MB (overlaps q/k/v/ctx)
    float* pooled         = (float*)(wsb + (56ull << 20));          // 16 KB
    __hip_bfloat16* wqt   = (__hip_bfloat16*)(wsb + (57ull << 20)); // 4 MB
    __hip_bfloat16* wkt   = (__hip_bfloat16*)(wsb + (61ull << 20)); // 4 MB
    __hip_bfloat16* wvt   = (__hip_bfloat16*)(wsb + (65ull << 20)); // 4 MB
    __hip_bfloat16* wot   = (__hip_bfloat16*)(wsb + (69ull << 20)); // 4 MB
    __hip_bfloat16* wit   = (__hip_bfloat16*)(wsb + (73ull << 20)); // 16 MB
    __hip_bfloat16* wft   = (__hip_bfloat16*)(wsb + (89ull << 20)); // 16 MB
    __hip_bfloat16* spt   = (__hip_bfloat16*)(wsb + (105ull << 20)); // 1 MB
    // total ~106 MB

    // ---- weight conversion (fp32 [K][N] -> bf16 [Npad][K]) ----
    wconv_kernel<<<dim3(16, 16, LL), 256, 0, stream>>>(Wq, wqt, DD, DD, DD);
    wconv_kernel<<<dim3(16, 16, LL), 256, 0, stream>>>(Wk, wkt, DD, DD, DD);
    wconv_kernel<<<dim3(16, 16, LL), 256, 0, stream>>>(Wv, wvt, DD, DD, DD);
    wconv_kernel<<<dim3(16, 16, LL), 256, 0, stream>>>(Wo, wot, DD, DD, DD);
    wconv_kernel<<<dim3(64, 16, LL), 256, 0, stream>>>(Wi, wit, DD, FF, FF);
    wconv_kernel<<<dim3(16, 64, LL), 256, 0, stream>>>(Wf, wft, FF, DD, DD);
    wconv_kernel<<<dim3(32, 16, 1),  256, 0, stream>>>(sp_w, spt, DD, 1000, 1024);

    proj_pe_kernel<<<MM, 256, 0, stream>>>(mel, proj_w, proj_b, pe, hbuf);

    dim3 g512(4, 64);     // N=512 tiles x M=8192 tiles

    for (int l = 0; l < LL; ++l) {
        size_t w512 = (size_t)l * DD * DD;
        size_t wiof = (size_t)l * FF * DD;   // wit: [2048][512] per layer
        size_t wfof = (size_t)l * DD * FF;   // wft: [512][2048] per layer

        ln_kernel<<<MM, 256, 0, stream>>>(hbuf, ln1_g + l * DD, ln1_b + l * DD, xb);

        gemm_bf16<2, false, false><<<g512, 256, 0, stream>>>(
            xb, wqt + w512, bq + l * DD, nullptr, nullptr, qbuf, MM, DD, DD);
        gemm_bf16<2, false, false><<<g512, 256, 0, stream>>>(
            xb, wkt + w512, bk + l * DD, nullptr, nullptr, kbuf, MM, DD, DD);
        gemm_bf16<3, false, false><<<g512, 256, 0, stream>>>(
            xb, wvt + w512, bv + l * DD, nullptr, nullptr, vtb, MM, DD, DD);

        attn_mfma<<<dim3(SS / 128, BB * HH), 256, 0, stream>>>(qbuf, kbuf, vtb, ctx);

        gemm_bf16<0, false, true><<<g512, 256, 0, stream>>>(
            ctx, wot + w512, bo + l * DD, hbuf, hbuf, nullptr, MM, DD, DD);

        ln_kernel<<<MM, 256, 0, stream>>>(hbuf, ln2_g + l * DD, ln2_b + l * DD, xb);

        gemm_bf16<1, true, false><<<dim3(16, 64), 256, 0, stream>>>(
            xb, wit + wiof, bi + l * FF, nullptr, nullptr, gbuf, MM, FF, DD);
        gemm_bf16<0, false, true><<<g512, 256, 0, stream>>>(
            gbuf, wft + wfof, bf + l * DD, hbuf, hbuf, nullptr, MM, DD, FF);
    }

    ln_kernel<<<MM, 256, 0, stream>>>(hbuf, lnf_g, lnf_b, xb);
    pool_kernel<<<BB, 512, 0, stream>>>(xb, pooled);
    heads_kernel<<<BB, 256, 0, stream>>>(pooled, lang_w, lang_b, int_w, int_b,
                                         emo_w, emo_b, out);

    // speech logits: [8192 x 1000], Npad=1024
    gemm_bf16<0, false, false><<<dim3(8, 64), 256, 0, stream>>>(
        xb, spt, sp_b, nullptr, out + 1264, nullptr, MM, 1000, DD);
}

// Round 4
// 1952.474 us; speedup vs baseline: 25.1637x; 1.2167x over previous
//
#include <hip/hip_runtime.h>
#include <hip/hip_bf16.h>
#include <math.h>

// Problem constants
#define DD   512
#define HH   8
#define DHH  64
#define LL   8
#define FF   2048
#define NMEL 80
#define BB   8
#define SS   1024
#define MM   (BB*SS)   // 8192 rows

typedef __attribute__((ext_vector_type(8))) short bf16x8;   // 8 bf16 = 4 VGPRs
typedef __attribute__((ext_vector_type(4))) float f32x4;    // MFMA C/D

#define GLOAD_LDS16(g, l) __builtin_amdgcn_global_load_lds( \
    (const __attribute__((address_space(1))) void*)(g),      \
    (__attribute__((address_space(3))) void*)(l), 16, 0, 0)

// ---------------------------------------------------------------------------
// proj + positional encoding (fp32, K=80 — tiny)
// ---------------------------------------------------------------------------
__global__ __launch_bounds__(256) void proj_pe_kernel(
    const float* __restrict__ mel, const float* __restrict__ pw,
    const float* __restrict__ pb, const float* __restrict__ pe,
    float* __restrict__ h)
{
    int row = blockIdx.x;
    int s = row & (SS - 1);
    __shared__ float m_s[NMEL];
    int t = threadIdx.x;
    if (t < NMEL) m_s[t] = mel[(size_t)row * NMEL + t];
    __syncthreads();
    for (int d = t; d < DD; d += 256) {
        float acc = pb[d] + pe[(size_t)s * DD + d];
        #pragma unroll 8
        for (int k = 0; k < NMEL; ++k)
            acc = fmaf(m_s[k], pw[(size_t)k * DD + d], acc);
        h[(size_t)row * DD + d] = acc;
    }
}

// ---------------------------------------------------------------------------
// LayerNorm (fp32 in -> bf16 out). One block (256 threads) per row.
// ---------------------------------------------------------------------------
__global__ __launch_bounds__(256) void ln_kernel(
    const float* __restrict__ in, const float* __restrict__ g,
    const float* __restrict__ bta, __hip_bfloat16* __restrict__ out)
{
    int row = blockIdx.x;
    const float* xr = in + (size_t)row * DD;
    int t = threadIdx.x;
    float x0 = xr[t], x1 = xr[t + 256];
    float s = x0 + x1;
    float ss = x0 * x0 + x1 * x1;
    #pragma unroll
    for (int off = 32; off; off >>= 1) {
        s  += __shfl_down(s, off);
        ss += __shfl_down(ss, off);
    }
    __shared__ float red1[4], red2[4];
    int lane = t & 63, w = t >> 6;
    if (lane == 0) { red1[w] = s; red2[w] = ss; }
    __syncthreads();
    s  = red1[0] + red1[1] + red1[2] + red1[3];
    ss = red2[0] + red2[1] + red2[2] + red2[3];
    float mu  = s * (1.f / DD);
    float var = ss * (1.f / DD) - mu * mu;
    float rstd = rsqrtf(var + 1e-5f);
    out[(size_t)row * DD + t]       = __float2bfloat16((x0 - mu) * rstd * g[t]       + bta[t]);
    out[(size_t)row * DD + t + 256] = __float2bfloat16((x1 - mu) * rstd * g[t + 256] + bta[t + 256]);
}

// ---------------------------------------------------------------------------
// Weight convert+transpose: fp32 [K][N] -> bf16 [rowoff+N rows][K] at row
// stride `rstride` per layer (blockIdx.z). Pads n>=N with zeros.
// ---------------------------------------------------------------------------
__global__ __launch_bounds__(256) void wconv_kernel(
    const float* __restrict__ in, __hip_bfloat16* __restrict__ out,
    int K, int N, int rstride, int rowoff)
{
    __shared__ float tile[32][33];
    size_t lin  = (size_t)blockIdx.z * K * N;
    size_t lout = (size_t)blockIdx.z * rstride * K + (size_t)rowoff * K;
    int tx = threadIdx.x & 31, ty = threadIdx.x >> 5;
    int n0 = blockIdx.x * 32, k0 = blockIdx.y * 32;
    #pragma unroll
    for (int i = 0; i < 32; i += 8) {
        int k = k0 + ty + i, n = n0 + tx;
        tile[ty + i][tx] = (n < N) ? in[lin + (size_t)k * N + n] : 0.f;
    }
    __syncthreads();
    #pragma unroll
    for (int i = 0; i < 32; i += 8) {
        int n = n0 + ty + i, k = k0 + tx;
        out[lout + (size_t)n * K + k] = __float2bfloat16(tile[tx][ty + i]);
    }
}

// ---------------------------------------------------------------------------
// bf16 MFMA GEMM: C[M,N] = A[M,K] @ Bt[N,K]^T (+bias) (+GELU) (+resid)
// 128x128 tile, BK=64, 512 threads = 8 waves (2m x 4n), wave tile 64x32,
// 4x2 16x16x32 frags per wave.
// OUTMODE: 0 = f32 flat (Cf), 1 = bf16 flat (O0),
//          2 = fused QKV: col<512 -> O0 heads[B,H,S,DH] (+b0),
//              col<1024 -> O1 heads (+b1), else O2 headsT[B,H,DH,S] (+b2)
// ---------------------------------------------------------------------------
template<int OUTMODE, bool GELU_EP, bool RESID>
__global__ __launch_bounds__(512) void gemm_bf16(
    const __hip_bfloat16* __restrict__ A,
    const __hip_bfloat16* __restrict__ Bt,
    const float* __restrict__ b0, const float* __restrict__ b1,
    const float* __restrict__ b2,
    const float* __restrict__ resid,
    float* __restrict__ Cf,
    __hip_bfloat16* __restrict__ O0, __hip_bfloat16* __restrict__ O1,
    __hip_bfloat16* __restrict__ O2,
    int M, int N, int K)
{
    __shared__ __align__(16) __hip_bfloat16 As[128 * 64];
    __shared__ __align__(16) __hip_bfloat16 Bs[128 * 64];
    int t = threadIdx.x;
    int w = t >> 6, lane = t & 63, g = lane >> 4, li = lane & 15;
    int wm = w >> 2, wn = w & 3;                 // 2 x 4 waves
    size_t bm = (size_t)blockIdx.y * 128;
    size_t bn = (size_t)blockIdx.x * 128;

    const f32x4 vzero = {0.f, 0.f, 0.f, 0.f};
    f32x4 acc[4][2];
    #pragma unroll
    for (int i = 0; i < 4; ++i)
        #pragma unroll
        for (int j = 0; j < 2; ++j) acc[i][j] = vzero;

    for (int k0 = 0; k0 < K; k0 += 64) {
        #pragma unroll
        for (int i = 0; i < 2; ++i) {
            int c = i * 512 + t;
            int row = c >> 3, col = (c & 7) << 3;
            GLOAD_LDS16(A + (bm + row) * (size_t)K + k0 + col, As + (size_t)c * 8);
        }
        #pragma unroll
        for (int i = 0; i < 2; ++i) {
            int c = i * 512 + t;
            int row = c >> 3, col = (c & 7) << 3;
            GLOAD_LDS16(Bt + (bn + row) * (size_t)K + k0 + col, Bs + (size_t)c * 8);
        }
        __syncthreads();
        #pragma unroll
        for (int kk = 0; kk < 2; ++kk) {
            bf16x8 af[4], bfr[2];
            #pragma unroll
            for (int mi = 0; mi < 4; ++mi)
                af[mi] = *reinterpret_cast<const bf16x8*>(As + (wm * 64 + mi * 16 + li) * 64 + kk * 32 + g * 8);
            #pragma unroll
            for (int ni = 0; ni < 2; ++ni)
                bfr[ni] = *reinterpret_cast<const bf16x8*>(Bs + (wn * 32 + ni * 16 + li) * 64 + kk * 32 + g * 8);
            #pragma unroll
            for (int mi = 0; mi < 4; ++mi)
                #pragma unroll
                for (int ni = 0; ni < 2; ++ni)
                    acc[mi][ni] = __builtin_amdgcn_mfma_f32_16x16x32_bf16(af[mi], bfr[ni], acc[mi][ni], 0, 0, 0);
        }
        __syncthreads();
    }

    #pragma unroll
    for (int mi = 0; mi < 4; ++mi) {
        #pragma unroll
        for (int ni = 0; ni < 2; ++ni) {
            f32x4 v = acc[mi][ni];
            int coll = wn * 32 + ni * 16 + li;
            size_t col = bn + coll;
            if ((int)col >= N) continue;
            float bv;
            int sel = 0, c = (int)col;
            if (OUTMODE == 2) {
                sel = (int)(col >> 9); c = (int)(col & 511);
                bv = (sel == 0) ? b0[c] : (sel == 1) ? b1[c] : b2[c];
            } else {
                bv = b0[col];
            }
            #pragma unroll
            for (int r = 0; r < 4; ++r) {
                size_t row = bm + wm * 64 + mi * 16 + g * 4 + r;
                float x = v[r] + bv;
                if (GELU_EP) x = 0.5f * x * (1.f + erff(x * 0.70710678118654752440f));
                if (RESID)   x += resid[row * (size_t)N + col];
                if (OUTMODE == 0) {
                    Cf[row * (size_t)N + col] = x;
                } else if (OUTMODE == 1) {
                    O0[row * (size_t)N + col] = __float2bfloat16(x);
                } else {
                    size_t b = row >> 10, s = row & (SS - 1);
                    size_t h = (size_t)(c >> 6), d = (size_t)(c & 63);
                    __hip_bfloat16 xb = __float2bfloat16(x);
                    if (sel == 0)      O0[((b * HH + h) << 16) + (s << 6) + d] = xb;
                    else if (sel == 1) O1[((b * HH + h) << 16) + (s << 6) + d] = xb;
                    else               O2[((b * HH + h) << 16) + (d << 10) + s] = xb;
                }
            }
        }
    }
}

// ---------------------------------------------------------------------------
// MFMA flash attention, 8 waves: wq=w&3 picks 32-query tile, wk=w>>2 picks
// KV half (512 keys). KV halves merged through LDS at the end.
// Q,K in [B,H,S,DH] bf16; V in [B,H,DH,S] bf16. ctx out bf16 [B,S,D].
// ---------------------------------------------------------------------------
__global__ __launch_bounds__(512, 4) void attn_mfma(
    const __hip_bfloat16* __restrict__ qb,
    const __hip_bfloat16* __restrict__ kb,
    const __hip_bfloat16* __restrict__ vtb,
    __hip_bfloat16* __restrict__ ctx)
{
    // Plds: [8][32][40] bf16 = 20,480 B ; comb (after loop): 4*64*48*4 = 49,152 B
    __shared__ __align__(16) char smem[49152];
    __hip_bfloat16 (*Plds)[32][40] = (__hip_bfloat16 (*)[32][40])smem;
    float* comb = (float*)smem;

    int t = threadIdx.x;
    int w = t >> 6, lane = t & 63, g = lane >> 4, li = lane & 15;
    int wq = w & 3, wk = w >> 2;
    int bh = blockIdx.y;
    int b = bh >> 3, h = bh & 7;
    int q0 = blockIdx.x * 128 + wq * 32;

    const __hip_bfloat16* Qp = qb  + ((size_t)bh << 16);
    const __hip_bfloat16* Kp = kb  + ((size_t)bh << 16);
    const __hip_bfloat16* Vp = vtb + ((size_t)bh << 16);

    bf16x8 qf[2][2];
    #pragma unroll
    for (int qt = 0; qt < 2; ++qt)
        #pragma unroll
        for (int kk = 0; kk < 2; ++kk)
            qf[qt][kk] = *reinterpret_cast<const bf16x8*>(
                Qp + (size_t)(q0 + qt * 16 + li) * DHH + kk * 32 + g * 8);

    const f32x4 vzero = {0.f, 0.f, 0.f, 0.f};
    f32x4 acc_o[2][4];
    float m_r[2][4], l_r[2][4];
    #pragma unroll
    for (int qt = 0; qt < 2; ++qt) {
        #pragma unroll
        for (int dt = 0; dt < 4; ++dt) acc_o[qt][dt] = vzero;
        #pragma unroll
        for (int r = 0; r < 4; ++r) { m_r[qt][r] = -1e30f; l_r[qt][r] = 0.f; }
    }

    const float csc = 0.125f * 1.44269504088896340736f;  // scale * log2(e)

    for (int it = 0; it < 16; ++it) {
        int ks0 = wk * 512 + it * 32;
        // ---- S = Q K^T ----
        f32x4 accs[2][2];
        #pragma unroll
        for (int qt = 0; qt < 2; ++qt)
            #pragma unroll
            for (int kt = 0; kt < 2; ++kt) accs[qt][kt] = vzero;
        #pragma unroll
        for (int kk = 0; kk < 2; ++kk) {
            bf16x8 kf[2];
            #pragma unroll
            for (int kt = 0; kt < 2; ++kt)
                kf[kt] = *reinterpret_cast<const bf16x8*>(
                    Kp + (size_t)(ks0 + kt * 16 + li) * DHH + kk * 32 + g * 8);
            #pragma unroll
            for (int qt = 0; qt < 2; ++qt)
                #pragma unroll
                for (int kt = 0; kt < 2; ++kt)
                    accs[qt][kt] = __builtin_amdgcn_mfma_f32_16x16x32_bf16(qf[qt][kk], kf[kt], accs[qt][kt], 0, 0, 0);
        }

        // ---- row max (base-2 domain) ----
        float mnew[2][4];
        #pragma unroll
        for (int qt = 0; qt < 2; ++qt)
            #pragma unroll
            for (int r = 0; r < 4; ++r)
                mnew[qt][r] = fmaxf(accs[qt][0][r], accs[qt][1][r]) * csc;
        #pragma unroll
        for (int mask = 1; mask < 16; mask <<= 1)
            #pragma unroll
            for (int qt = 0; qt < 2; ++qt)
                #pragma unroll
                for (int r = 0; r < 4; ++r)
                    mnew[qt][r] = fmaxf(mnew[qt][r], __shfl_xor(mnew[qt][r], mask));

        // ---- defer-max: only rescale when max grows materially ----
        bool grow = false;
        #pragma unroll
        for (int qt = 0; qt < 2; ++qt)
            #pragma unroll
            for (int r = 0; r < 4; ++r)
                grow = grow || (mnew[qt][r] > m_r[qt][r] + 11.0f);
        if (__any(grow)) {
            #pragma unroll
            for (int qt = 0; qt < 2; ++qt)
                #pragma unroll
                for (int r = 0; r < 4; ++r) {
                    float mn = fmaxf(m_r[qt][r], mnew[qt][r]);
                    float alpha = exp2f(m_r[qt][r] - mn);
                    m_r[qt][r] = mn;
                    l_r[qt][r] *= alpha;
                    #pragma unroll
                    for (int dt = 0; dt < 4; ++dt)
                        acc_o[qt][dt][r] *= alpha;
                }
        }

        // ---- P = exp2(s - m), store to LDS, accumulate row sums ----
        float rs[2][4] = {};
        #pragma unroll
        for (int qt = 0; qt < 2; ++qt)
            #pragma unroll
            for (int kt = 0; kt < 2; ++kt)
                #pragma unroll
                for (int r = 0; r < 4; ++r) {
                    float p = exp2f(accs[qt][kt][r] * csc - m_r[qt][r]);
                    rs[qt][r] += p;
                    Plds[w][qt * 16 + g * 4 + r][kt * 16 + li] = __float2bfloat16(p);
                }
        #pragma unroll
        for (int mask = 1; mask < 16; mask <<= 1)
            #pragma unroll
            for (int qt = 0; qt < 2; ++qt)
                #pragma unroll
                for (int r = 0; r < 4; ++r)
                    rs[qt][r] += __shfl_xor(rs[qt][r], mask);
        #pragma unroll
        for (int qt = 0; qt < 2; ++qt)
            #pragma unroll
            for (int r = 0; r < 4; ++r)
                l_r[qt][r] += rs[qt][r];

        __builtin_amdgcn_wave_barrier();

        // ---- O += P V ----
        bf16x8 pf[2];
        #pragma unroll
        for (int qt = 0; qt < 2; ++qt)
            pf[qt] = *reinterpret_cast<const bf16x8*>(&Plds[w][qt * 16 + li][g * 8]);
        #pragma unroll
        for (int dt = 0; dt < 4; ++dt) {
            bf16x8 vf = *reinterpret_cast<const bf16x8*>(
                Vp + (size_t)(dt * 16 + li) * SS + ks0 + g * 8);
            #pragma unroll
            for (int qt = 0; qt < 2; ++qt)
                acc_o[qt][dt] = __builtin_amdgcn_mfma_f32_16x16x32_bf16(pf[qt], vf, acc_o[qt][dt], 0, 0, 0);
        }
        __builtin_amdgcn_wave_barrier();
    }

    // ---- merge the two KV halves through LDS ----
    __syncthreads();
    if (wk == 1) {
        float* cb = comb + ((size_t)(w - 4) * 64 + lane) * 48;
        #pragma unroll
        for (int qt = 0; qt < 2; ++qt)
            #pragma unroll
            for (int dt = 0; dt < 4; ++dt)
                *reinterpret_cast<f32x4*>(cb + qt * 16 + dt * 4) = acc_o[qt][dt];
        #pragma unroll
        for (int qt = 0; qt < 2; ++qt)
            #pragma unroll
            for (int r = 0; r < 4; ++r) {
                cb[32 + qt * 4 + r] = m_r[qt][r];
                cb[40 + qt * 4 + r] = l_r[qt][r];
            }
    }
    __syncthreads();
    if (wk == 0) {
        float* cb = comb + ((size_t)w * 64 + lane) * 48;
        float a1[2][4], a2[2][4], inv[2][4];
        #pragma unroll
        for (int qt = 0; qt < 2; ++qt)
            #pragma unroll
            for (int r = 0; r < 4; ++r) {
                float m2 = cb[32 + qt * 4 + r];
                float l2 = cb[40 + qt * 4 + r];
                float mg = fmaxf(m_r[qt][r], m2);
                a1[qt][r] = exp2f(m_r[qt][r] - mg);
                a2[qt][r] = exp2f(m2 - mg);
                inv[qt][r] = 1.f / (l_r[qt][r] * a1[qt][r] + l2 * a2[qt][r]);
            }
        #pragma unroll
        for (int qt = 0; qt < 2; ++qt)
            #pragma unroll
            for (int dt = 0; dt < 4; ++dt) {
                f32x4 ob = *reinterpret_cast<const f32x4*>(cb + qt * 16 + dt * 4);
                #pragma unroll
                for (int r = 0; r < 4; ++r) {
                    int q = q0 + qt * 16 + g * 4 + r;
                    int d = dt * 16 + li;
                    float o = (acc_o[qt][dt][r] * a1[qt][r] + ob[r] * a2[qt][r]) * inv[qt][r];
                    ctx[((size_t)(b * SS + q)) * DD + h * DHH + d] = __float2bfloat16(o);
                }
            }
    }
}

// ---------------------------------------------------------------------------
// Mean pool (bf16 in, fp32 out)
// ---------------------------------------------------------------------------
__global__ __launch_bounds__(512) void pool_kernel(
    const __hip_bfloat16* __restrict__ hf, float* __restrict__ pooled)
{
    int b = blockIdx.x;
    int d = threadIdx.x;
    float acc = 0.f;
    for (int s = 0; s < SS; ++s)
        acc += __bfloat162float(hf[((size_t)(b * SS + s)) * DD + d]);
    pooled[b * DD + d] = acc * (1.f / SS);
}

// ---------------------------------------------------------------------------
// Small heads (fp32)
// ---------------------------------------------------------------------------
__global__ __launch_bounds__(256) void heads_kernel(
    const float* __restrict__ pooled,
    const float* __restrict__ lw, const float* __restrict__ lb,
    const float* __restrict__ iw, const float* __restrict__ ib,
    const float* __restrict__ ew, const float* __restrict__ eb,
    float* __restrict__ out)
{
    int b = blockIdx.x;
    __shared__ float ps[DD];
    int t = threadIdx.x;
    ps[t] = pooled[b * DD + t];
    ps[t + 256] = pooled[b * DD + t + 256];
    __syncthreads();
    if (t < 158) {
        const float* wptr; const float* bptr; float* optr; int n; int j;
        if (t < 100)      { j = t;       wptr = lw; bptr = lb; optr = out;        n = 100; }
        else if (t < 150) { j = t - 100; wptr = iw; bptr = ib; optr = out + 800;  n = 50;  }
        else              { j = t - 150; wptr = ew; bptr = eb; optr = out + 1200; n = 8;   }
        float acc = bptr[j];
        for (int k2 = 0; k2 < DD; ++k2)
            acc = fmaf(ps[k2], wptr[(size_t)k2 * n + j], acc);
        optr[b * n + j] = acc;
    }
}

// ---------------------------------------------------------------------------
extern "C" void kernel_launch(void* const* d_in, const int* in_sizes, int n_in,
                              void* d_out, int out_size, void* d_ws, size_t ws_size,
                              hipStream_t stream)
{
    const float* mel    = (const float*)d_in[0];
    const float* pe     = (const float*)d_in[1];
    const float* proj_w = (const float*)d_in[2];
    const float* proj_b = (const float*)d_in[3];
    const float* Wq     = (const float*)d_in[4];
    const float* bq     = (const float*)d_in[5];
    const float* Wk     = (const float*)d_in[6];
    const float* bk     = (const float*)d_in[7];
    const float* Wv     = (const float*)d_in[8];
    const float* bv     = (const float*)d_in[9];
    const float* Wo     = (const float*)d_in[10];
    const float* bo     = (const float*)d_in[11];
    const float* ln1_g  = (const float*)d_in[12];
    const float* ln1_b  = (const float*)d_in[13];
    const float* ln2_g  = (const float*)d_in[14];
    const float* ln2_b  = (const float*)d_in[15];
    const float* Wi     = (const float*)d_in[16];
    const float* bi     = (const float*)d_in[17];
    const float* Wf     = (const float*)d_in[18];
    const float* bf     = (const float*)d_in[19];
    const float* lnf_g  = (const float*)d_in[20];
    const float* lnf_b  = (const float*)d_in[21];
    const float* lang_w = (const float*)d_in[22];
    const float* lang_b = (const float*)d_in[23];
    const float* int_w  = (const float*)d_in[24];
    const float* int_b  = (const float*)d_in[25];
    const float* emo_w  = (const float*)d_in[26];
    const float* emo_b  = (const float*)d_in[27];
    const float* sp_w   = (const float*)d_in[28];
    const float* sp_b   = (const float*)d_in[29];

    float* out = (float*)d_out;
    char* wsb = (char*)d_ws;

    const size_t MB = 1ull << 20;
    float* hbuf           = (float*)(wsb);                    // 0..16 MB residual f32
    __hip_bfloat16* xb    = (__hip_bfloat16*)(wsb + 16 * MB); // 16..24 LN out bf16
    __hip_bfloat16* qbuf  = (__hip_bfloat16*)(wsb + 24 * MB); // 24..32
    __hip_bfloat16* kbuf  = (__hip_bfloat16*)(wsb + 32 * MB); // 32..40
    __hip_bfloat16* vtb   = (__hip_bfloat16*)(wsb + 40 * MB); // 40..48
    __hip_bfloat16* ctx   = (__hip_bfloat16*)(wsb + 48 * MB); // 48..56
    __hip_bfloat16* gbuf  = (__hip_bfloat16*)(wsb + 24 * MB); // 24..56 (overlaps q/k/v/ctx)
    float* pooled         = (float*)(wsb + 56 * MB);          // 16 KB
    __hip_bfloat16* wqkv  = (__hip_bfloat16*)(wsb + 57 * MB); // 57..69.6: [L][1536][512]
    __hip_bfloat16* wot   = (__hip_bfloat16*)(wsb + 70 * MB); // 70..74
    __hip_bfloat16* wit   = (__hip_bfloat16*)(wsb + 74 * MB); // 74..90
    __hip_bfloat16* wft   = (__hip_bfloat16*)(wsb + 90 * MB); // 90..106
    __hip_bfloat16* spt   = (__hip_bfloat16*)(wsb + 107 * MB); // 107..108 (CLEAR of wft!)
    // total 108 MB

    // ---- weight conversion ----
    wconv_kernel<<<dim3(16, 16, LL), 256, 0, stream>>>(Wq, wqkv, DD, DD, 1536, 0);
    wconv_kernel<<<dim3(16, 16, LL), 256, 0, stream>>>(Wk, wqkv, DD, DD, 1536, 512);
    wconv_kernel<<<dim3(16, 16, LL), 256, 0, stream>>>(Wv, wqkv, DD, DD, 1536, 1024);
    wconv_kernel<<<dim3(16, 16, LL), 256, 0, stream>>>(Wo, wot, DD, DD, DD, 0);
    wconv_kernel<<<dim3(64, 16, LL), 256, 0, stream>>>(Wi, wit, DD, FF, FF, 0);
    wconv_kernel<<<dim3(16, 64, LL), 256, 0, stream>>>(Wf, wft, FF, DD, DD, 0);
    wconv_kernel<<<dim3(32, 16, 1),  256, 0, stream>>>(sp_w, spt, DD, 1000, 1024, 0);

    proj_pe_kernel<<<MM, 256, 0, stream>>>(mel, proj_w, proj_b, pe, hbuf);

    dim3 g512(4, 64);

    for (int l = 0; l < LL; ++l) {
        const __hip_bfloat16* wqkv_l = wqkv + (size_t)l * 1536 * DD;
        const __hip_bfloat16* wot_l  = wot  + (size_t)l * DD * DD;
        const __hip_bfloat16* wit_l  = wit  + (size_t)l * FF * DD;
        const __hip_bfloat16* wft_l  = wft  + (size_t)l * DD * FF;

        ln_kernel<<<MM, 256, 0, stream>>>(hbuf, ln1_g + l * DD, ln1_b + l * DD, xb);

        gemm_bf16<2, false, false><<<dim3(12, 64), 512, 0, stream>>>(
            xb, wqkv_l, bq + l * DD, bk + l * DD, bv + l * DD,
            nullptr, nullptr, qbuf, kbuf, vtb, MM, 1536, DD);

        attn_mfma<<<dim3(SS / 128, BB * HH), 512, 0, stream>>>(qbuf, kbuf, vtb, ctx);

        gemm_bf16<0, false, true><<<g512, 512, 0, stream>>>(
            ctx, wot_l, bo + l * DD, nullptr, nullptr,
            hbuf, hbuf, nullptr, nullptr, nullptr, MM, DD, DD);

        ln_kernel<<<MM, 256, 0, stream>>>(hbuf, ln2_g + l * DD, ln2_b + l * DD, xb);

        gemm_bf16<1, true, false><<<dim3(16, 64), 512, 0, stream>>>(
            xb, wit_l, bi + l * FF, nullptr, nullptr,
            nullptr, nullptr, gbuf, nullptr, nullptr, MM, FF, DD);
        gemm_bf16<0, false, true><<<g512, 512, 0, stream>>>(
            gbuf, wft_l, bf + l * DD, nullptr, nullptr,
            hbuf, hbuf, nullptr, nullptr, nullptr, MM, DD, FF);
    }

    ln_kernel<<<MM, 256, 0, stream>>>(hbuf, lnf_g, lnf_b, xb);
    pool_kernel<<<BB, 512, 0, stream>>>(xb, pooled);
    heads_kernel<<<BB, 256, 0, stream>>>(pooled, lang_w, lang_b, int_w, int_b,
                                         emo_w, emo_b, out);

    gemm_bf16<0, false, false><<<dim3(8, 64), 512, 0, stream>>>(
        xb, spt, sp_b, nullptr, nullptr,
        nullptr, out + 1264, nullptr, nullptr, nullptr, MM, 1000, DD);
}

// Round 5
// 1884.510 us; speedup vs baseline: 26.0713x; 1.0361x over previous
//
#include <hip/hip_runtime.h>
#include <hip/hip_bf16.h>
#include <math.h>

// Problem constants
#define DD   512
#define HH   8
#define DHH  64
#define LL   8
#define FF   2048
#define NMEL 80
#define BB   8
#define SS   1024
#define MM   (BB*SS)   // 8192 rows

typedef __attribute__((ext_vector_type(8))) short bf16x8;   // 8 bf16 = 4 VGPRs
typedef __attribute__((ext_vector_type(4))) float f32x4;    // MFMA C/D
typedef __attribute__((ext_vector_type(4))) unsigned short u16x4;

#define GLOAD_LDS16(g, l) __builtin_amdgcn_global_load_lds( \
    (const __attribute__((address_space(1))) void*)(g),      \
    (__attribute__((address_space(3))) void*)(l), 16, 0, 0)

__device__ __forceinline__ unsigned short f2bf(float x) {
    __hip_bfloat16 b = __float2bfloat16(x);
    return *reinterpret_cast<unsigned short*>(&b);
}

// ---------------------------------------------------------------------------
// proj + positional encoding (fp32, K=80 — tiny)
// ---------------------------------------------------------------------------
__global__ __launch_bounds__(256) void proj_pe_kernel(
    const float* __restrict__ mel, const float* __restrict__ pw,
    const float* __restrict__ pb, const float* __restrict__ pe,
    float* __restrict__ h)
{
    int row = blockIdx.x;
    int s = row & (SS - 1);
    __shared__ float m_s[NMEL];
    int t = threadIdx.x;
    if (t < NMEL) m_s[t] = mel[(size_t)row * NMEL + t];
    __syncthreads();
    for (int d = t; d < DD; d += 256) {
        float acc = pb[d] + pe[(size_t)s * DD + d];
        #pragma unroll 8
        for (int k = 0; k < NMEL; ++k)
            acc = fmaf(m_s[k], pw[(size_t)k * DD + d], acc);
        h[(size_t)row * DD + d] = acc;
    }
}

// ---------------------------------------------------------------------------
// LayerNorm (fp32 in -> bf16 out). One block (256 threads) per row.
// ---------------------------------------------------------------------------
__global__ __launch_bounds__(256) void ln_kernel(
    const float* __restrict__ in, const float* __restrict__ g,
    const float* __restrict__ bta, __hip_bfloat16* __restrict__ out)
{
    int row = blockIdx.x;
    const float* xr = in + (size_t)row * DD;
    int t = threadIdx.x;
    float x0 = xr[t], x1 = xr[t + 256];
    float s = x0 + x1;
    float ss = x0 * x0 + x1 * x1;
    #pragma unroll
    for (int off = 32; off; off >>= 1) {
        s  += __shfl_down(s, off);
        ss += __shfl_down(ss, off);
    }
    __shared__ float red1[4], red2[4];
    int lane = t & 63, w = t >> 6;
    if (lane == 0) { red1[w] = s; red2[w] = ss; }
    __syncthreads();
    s  = red1[0] + red1[1] + red1[2] + red1[3];
    ss = red2[0] + red2[1] + red2[2] + red2[3];
    float mu  = s * (1.f / DD);
    float var = ss * (1.f / DD) - mu * mu;
    float rstd = rsqrtf(var + 1e-5f);
    out[(size_t)row * DD + t]       = __float2bfloat16((x0 - mu) * rstd * g[t]       + bta[t]);
    out[(size_t)row * DD + t + 256] = __float2bfloat16((x1 - mu) * rstd * g[t + 256] + bta[t + 256]);
}

// ---------------------------------------------------------------------------
// Weight convert+transpose: fp32 [K][N] -> bf16 [rowoff+N rows][K] at row
// stride `rstride` per layer (blockIdx.z). Pads n>=N with zeros.
// ---------------------------------------------------------------------------
__global__ __launch_bounds__(256) void wconv_kernel(
    const float* __restrict__ in, __hip_bfloat16* __restrict__ out,
    int K, int N, int rstride, int rowoff)
{
    __shared__ float tile[32][33];
    size_t lin  = (size_t)blockIdx.z * K * N;
    size_t lout = (size_t)blockIdx.z * rstride * K + (size_t)rowoff * K;
    int tx = threadIdx.x & 31, ty = threadIdx.x >> 5;
    int n0 = blockIdx.x * 32, k0 = blockIdx.y * 32;
    #pragma unroll
    for (int i = 0; i < 32; i += 8) {
        int k = k0 + ty + i, n = n0 + tx;
        tile[ty + i][tx] = (n < N) ? in[lin + (size_t)k * N + n] : 0.f;
    }
    __syncthreads();
    #pragma unroll
    for (int i = 0; i < 32; i += 8) {
        int n = n0 + ty + i, k = k0 + tx;
        out[lout + (size_t)n * K + k] = __float2bfloat16(tile[tx][ty + i]);
    }
}

// ---------------------------------------------------------------------------
// bf16 MFMA GEMM: C[M,N] = A[M,K] @ Bt[N,K]^T (+bias) (+GELU) (+resid)
// 128x128 tile, BK=64, 512 threads = 8 waves (2m x 4n), wave tile 64x32,
// 4x2 16x16x32 frags per wave.
// OUTMODE: 0 = f32 flat (Cf), 1 = bf16 flat (O0),
//          2 = fused QKV: col<512 -> O0 heads[B,H,S,DH] (+b0),
//              col<1024 -> O1 heads (+b1), else O2 headsT[B,H,DH,S] (+b2)
// ---------------------------------------------------------------------------
template<int OUTMODE, bool GELU_EP, bool RESID>
__global__ __launch_bounds__(512) void gemm_bf16(
    const __hip_bfloat16* __restrict__ A,
    const __hip_bfloat16* __restrict__ Bt,
    const float* __restrict__ b0, const float* __restrict__ b1,
    const float* __restrict__ b2,
    const float* __restrict__ resid,
    float* __restrict__ Cf,
    __hip_bfloat16* __restrict__ O0, __hip_bfloat16* __restrict__ O1,
    __hip_bfloat16* __restrict__ O2,
    int M, int N, int K)
{
    __shared__ __align__(16) __hip_bfloat16 As[128 * 64];
    __shared__ __align__(16) __hip_bfloat16 Bs[128 * 64];
    int t = threadIdx.x;
    int w = t >> 6, lane = t & 63, g = lane >> 4, li = lane & 15;
    int wm = w >> 2, wn = w & 3;                 // 2 x 4 waves
    size_t bm = (size_t)blockIdx.y * 128;
    size_t bn = (size_t)blockIdx.x * 128;

    const f32x4 vzero = {0.f, 0.f, 0.f, 0.f};
    f32x4 acc[4][2];
    #pragma unroll
    for (int i = 0; i < 4; ++i)
        #pragma unroll
        for (int j = 0; j < 2; ++j) acc[i][j] = vzero;

    for (int k0 = 0; k0 < K; k0 += 64) {
        #pragma unroll
        for (int i = 0; i < 2; ++i) {
            int c = i * 512 + t;
            int row = c >> 3, col = (c & 7) << 3;
            GLOAD_LDS16(A + (bm + row) * (size_t)K + k0 + col, As + (size_t)c * 8);
        }
        #pragma unroll
        for (int i = 0; i < 2; ++i) {
            int c = i * 512 + t;
            int row = c >> 3, col = (c & 7) << 3;
            GLOAD_LDS16(Bt + (bn + row) * (size_t)K + k0 + col, Bs + (size_t)c * 8);
        }
        __syncthreads();
        #pragma unroll
        for (int kk = 0; kk < 2; ++kk) {
            bf16x8 af[4], bfr[2];
            #pragma unroll
            for (int mi = 0; mi < 4; ++mi)
                af[mi] = *reinterpret_cast<const bf16x8*>(As + (wm * 64 + mi * 16 + li) * 64 + kk * 32 + g * 8);
            #pragma unroll
            for (int ni = 0; ni < 2; ++ni)
                bfr[ni] = *reinterpret_cast<const bf16x8*>(Bs + (wn * 32 + ni * 16 + li) * 64 + kk * 32 + g * 8);
            #pragma unroll
            for (int mi = 0; mi < 4; ++mi)
                #pragma unroll
                for (int ni = 0; ni < 2; ++ni)
                    acc[mi][ni] = __builtin_amdgcn_mfma_f32_16x16x32_bf16(af[mi], bfr[ni], acc[mi][ni], 0, 0, 0);
        }
        __syncthreads();
    }

    #pragma unroll
    for (int mi = 0; mi < 4; ++mi) {
        #pragma unroll
        for (int ni = 0; ni < 2; ++ni) {
            f32x4 v = acc[mi][ni];
            int coll = wn * 32 + ni * 16 + li;
            size_t col = bn + coll;
            if ((int)col >= N) continue;
            float bv;
            int sel = 0, c = (int)col;
            if (OUTMODE == 2) {
                sel = (int)(col >> 9); c = (int)(col & 511);
                bv = (sel == 0) ? b0[c] : (sel == 1) ? b1[c] : b2[c];
            } else {
                bv = b0[col];
            }
            #pragma unroll
            for (int r = 0; r < 4; ++r) {
                size_t row = bm + wm * 64 + mi * 16 + g * 4 + r;
                float x = v[r] + bv;
                if (GELU_EP) x = 0.5f * x * (1.f + erff(x * 0.70710678118654752440f));
                if (RESID)   x += resid[row * (size_t)N + col];
                if (OUTMODE == 0) {
                    Cf[row * (size_t)N + col] = x;
                } else if (OUTMODE == 1) {
                    O0[row * (size_t)N + col] = __float2bfloat16(x);
                } else {
                    size_t b = row >> 10, s = row & (SS - 1);
                    size_t h = (size_t)(c >> 6), d = (size_t)(c & 63);
                    __hip_bfloat16 xb = __float2bfloat16(x);
                    if (sel == 0)      O0[((b * HH + h) << 16) + (s << 6) + d] = xb;
                    else if (sel == 1) O1[((b * HH + h) << 16) + (s << 6) + d] = xb;
                    else               O2[((b * HH + h) << 16) + (d << 10) + s] = xb;
                }
            }
        }
    }
}

// ---------------------------------------------------------------------------
// MFMA flash attention v3 — SWAPPED operand order so softmax is lane-local.
// 8 waves: wq=w&3 picks 32-query tile, wk=w>>2 picks KV half (512 keys).
// S^T = mfma(K,Q): lane holds S[k=g*4+r][q=li] -> row-reduce = 7 in-reg ops
// + 2 shuffles; m/l/alpha are per-lane scalars. P packed to LDS as b64.
// O^T = mfma(V^T, P): same read addressing as before; ctx written as 8B packs.
// Q,K in [B,H,S,DH] bf16; V in [B,H,DH,S] bf16. ctx out bf16 [B,S,D].
// ---------------------------------------------------------------------------
__global__ __launch_bounds__(512, 4) void attn_mfma(
    const __hip_bfloat16* __restrict__ qb,
    const __hip_bfloat16* __restrict__ kb,
    const __hip_bfloat16* __restrict__ vtb,
    __hip_bfloat16* __restrict__ ctx)
{
    // Plds: [8 waves][32 q-rows][40 k-pad] ushort = 20,480 B
    // comb (after loop): 4*64 lanes * 36 floats = 36,864 B
    __shared__ __align__(16) char smem[49152];
    unsigned short (*Plds)[32][40] = (unsigned short (*)[32][40])smem;
    float* comb = (float*)smem;

    int t = threadIdx.x;
    int w = t >> 6, lane = t & 63, g = lane >> 4, li = lane & 15;
    int wq = w & 3, wk = w >> 2;
    int bh = blockIdx.y;
    int b = bh >> 3, h = bh & 7;
    int q0 = blockIdx.x * 128 + wq * 32;

    const __hip_bfloat16* Qp = qb  + ((size_t)bh << 16);
    const __hip_bfloat16* Kp = kb  + ((size_t)bh << 16);
    const __hip_bfloat16* Vp = vtb + ((size_t)bh << 16);

    // Q fragments (B-operand rows = q)
    bf16x8 qf[2][2];
    #pragma unroll
    for (int qt = 0; qt < 2; ++qt)
        #pragma unroll
        for (int kk = 0; kk < 2; ++kk)
            qf[qt][kk] = *reinterpret_cast<const bf16x8*>(
                Qp + (size_t)(q0 + qt * 16 + li) * DHH + kk * 32 + g * 8);

    const f32x4 vzero = {0.f, 0.f, 0.f, 0.f};
    // acc_oT[qt][dt]: lane holds O[q=q0+qt*16+li][d=dt*16+g*4+r]
    f32x4 acc_oT[2][4];
    float m_r[2], l_r[2];
    #pragma unroll
    for (int qt = 0; qt < 2; ++qt) {
        #pragma unroll
        for (int dt = 0; dt < 4; ++dt) acc_oT[qt][dt] = vzero;
        m_r[qt] = -1e30f; l_r[qt] = 0.f;
    }

    const float csc = 0.125f * 1.44269504088896340736f;  // scale * log2(e)

    for (int it = 0; it < 16; ++it) {
        int ks0 = wk * 512 + it * 32;
        // ---- S^T = K Q^T : accs[qt][kt], lane = S[k=ks0+kt*16+g*4+r][q=li] ----
        f32x4 accs[2][2];
        #pragma unroll
        for (int qt = 0; qt < 2; ++qt)
            #pragma unroll
            for (int kt = 0; kt < 2; ++kt) accs[qt][kt] = vzero;
        #pragma unroll
        for (int kk = 0; kk < 2; ++kk) {
            bf16x8 kf[2];
            #pragma unroll
            for (int kt = 0; kt < 2; ++kt)
                kf[kt] = *reinterpret_cast<const bf16x8*>(
                    Kp + (size_t)(ks0 + kt * 16 + li) * DHH + kk * 32 + g * 8);
            #pragma unroll
            for (int qt = 0; qt < 2; ++qt)
                #pragma unroll
                for (int kt = 0; kt < 2; ++kt)
                    accs[qt][kt] = __builtin_amdgcn_mfma_f32_16x16x32_bf16(kf[kt], qf[qt][kk], accs[qt][kt], 0, 0, 0);
        }

        // ---- per-q max over 32 raw scores (8 in-reg + 2 shuffles) ----
        float mnew[2];
        #pragma unroll
        for (int qt = 0; qt < 2; ++qt) {
            float a0 = fmaxf(fmaxf(accs[qt][0][0], accs[qt][0][1]),
                             fmaxf(accs[qt][0][2], accs[qt][0][3]));
            float a1 = fmaxf(fmaxf(accs[qt][1][0], accs[qt][1][1]),
                             fmaxf(accs[qt][1][2], accs[qt][1][3]));
            float m = fmaxf(a0, a1);
            m = fmaxf(m, __shfl_xor(m, 16));
            m = fmaxf(m, __shfl_xor(m, 32));
            mnew[qt] = m * csc;                 // scaled (base-2) domain
        }

        // ---- defer-max: only rescale when max grows materially ----
        bool grow = (mnew[0] > m_r[0] + 11.0f) || (mnew[1] > m_r[1] + 11.0f);
        if (__any(grow)) {
            #pragma unroll
            for (int qt = 0; qt < 2; ++qt) {
                float mn = fmaxf(m_r[qt], mnew[qt]);
                float alpha = exp2f(m_r[qt] - mn);
                m_r[qt] = mn;
                l_r[qt] *= alpha;
                #pragma unroll
                for (int dt = 0; dt < 4; ++dt)
                    #pragma unroll
                    for (int r = 0; r < 4; ++r)
                        acc_oT[qt][dt][r] *= alpha;
            }
        }

        // ---- P = exp2(s*csc - m), packed b64 store; row sums ----
        float rs[2] = {0.f, 0.f};
        #pragma unroll
        for (int qt = 0; qt < 2; ++qt) {
            #pragma unroll
            for (int kt = 0; kt < 2; ++kt) {
                u16x4 pk;
                #pragma unroll
                for (int r = 0; r < 4; ++r) {
                    float p = exp2f(fmaf(accs[qt][kt][r], csc, -m_r[qt]));
                    rs[qt] += p;
                    pk[r] = f2bf(p);
                }
                *reinterpret_cast<u16x4*>(&Plds[w][qt * 16 + li][kt * 16 + g * 4]) = pk;
            }
            float s = rs[qt];
            s += __shfl_xor(s, 16);
            s += __shfl_xor(s, 32);
            l_r[qt] += s;
        }

        __builtin_amdgcn_wave_barrier();

        // ---- O^T += V^T P^T : A = V^T rows d, B = P rows q ----
        bf16x8 pf[2];
        #pragma unroll
        for (int qt = 0; qt < 2; ++qt)
            pf[qt] = *reinterpret_cast<const bf16x8*>(&Plds[w][qt * 16 + li][g * 8]);
        #pragma unroll
        for (int dt = 0; dt < 4; ++dt) {
            bf16x8 vf = *reinterpret_cast<const bf16x8*>(
                Vp + (size_t)(dt * 16 + li) * SS + ks0 + g * 8);
            #pragma unroll
            for (int qt = 0; qt < 2; ++qt)
                acc_oT[qt][dt] = __builtin_amdgcn_mfma_f32_16x16x32_bf16(vf, pf[qt], acc_oT[qt][dt], 0, 0, 0);
        }
        __builtin_amdgcn_wave_barrier();
    }

    // ---- merge the two KV halves through LDS (36 floats per lane) ----
    __syncthreads();
    if (wk == 1) {
        float* cb = comb + ((size_t)(w - 4) * 64 + lane) * 36;
        #pragma unroll
        for (int qt = 0; qt < 2; ++qt)
            #pragma unroll
            for (int dt = 0; dt < 4; ++dt)
                *reinterpret_cast<f32x4*>(cb + qt * 16 + dt * 4) = acc_oT[qt][dt];
        #pragma unroll
        for (int qt = 0; qt < 2; ++qt) {
            cb[32 + qt] = m_r[qt];
            cb[34 + qt] = l_r[qt];
        }
    }
    __syncthreads();
    if (wk == 0) {
        float* cb = comb + ((size_t)w * 64 + lane) * 36;
        #pragma unroll
        for (int qt = 0; qt < 2; ++qt) {
            float m2 = cb[32 + qt];
            float l2 = cb[34 + qt];
            float mg = fmaxf(m_r[qt], m2);
            float a1 = exp2f(m_r[qt] - mg);
            float a2 = exp2f(m2 - mg);
            float inv = 1.f / (l_r[qt] * a1 + l2 * a2);
            int q = q0 + qt * 16 + li;
            #pragma unroll
            for (int dt = 0; dt < 4; ++dt) {
                f32x4 ob = *reinterpret_cast<const f32x4*>(cb + qt * 16 + dt * 4);
                u16x4 pk;
                #pragma unroll
                for (int r = 0; r < 4; ++r)
                    pk[r] = f2bf((acc_oT[qt][dt][r] * a1 + ob[r] * a2) * inv);
                *reinterpret_cast<u16x4*>(
                    &ctx[((size_t)(b * SS + q)) * DD + h * DHH + dt * 16 + g * 4]) = pk;
            }
        }
    }
}

// ---------------------------------------------------------------------------
// Mean pool (bf16 in, fp32 out)
// ---------------------------------------------------------------------------
__global__ __launch_bounds__(512) void pool_kernel(
    const __hip_bfloat16* __restrict__ hf, float* __restrict__ pooled)
{
    int b = blockIdx.x;
    int d = threadIdx.x;
    float acc = 0.f;
    for (int s = 0; s < SS; ++s)
        acc += __bfloat162float(hf[((size_t)(b * SS + s)) * DD + d]);
    pooled[b * DD + d] = acc * (1.f / SS);
}

// ---------------------------------------------------------------------------
// Small heads (fp32)
// ---------------------------------------------------------------------------
__global__ __launch_bounds__(256) void heads_kernel(
    const float* __restrict__ pooled,
    const float* __restrict__ lw, const float* __restrict__ lb,
    const float* __restrict__ iw, const float* __restrict__ ib,
    const float* __restrict__ ew, const float* __restrict__ eb,
    float* __restrict__ out)
{
    int b = blockIdx.x;
    __shared__ float ps[DD];
    int t = threadIdx.x;
    ps[t] = pooled[b * DD + t];
    ps[t + 256] = pooled[b * DD + t + 256];
    __syncthreads();
    if (t < 158) {
        const float* wptr; const float* bptr; float* optr; int n; int j;
        if (t < 100)      { j = t;       wptr = lw; bptr = lb; optr = out;        n = 100; }
        else if (t < 150) { j = t - 100; wptr = iw; bptr = ib; optr = out + 800;  n = 50;  }
        else              { j = t - 150; wptr = ew; bptr = eb; optr = out + 1200; n = 8;   }
        float acc = bptr[j];
        for (int k2 = 0; k2 < DD; ++k2)
            acc = fmaf(ps[k2], wptr[(size_t)k2 * n + j], acc);
        optr[b * n + j] = acc;
    }
}

// ---------------------------------------------------------------------------
extern "C" void kernel_launch(void* const* d_in, const int* in_sizes, int n_in,
                              void* d_out, int out_size, void* d_ws, size_t ws_size,
                              hipStream_t stream)
{
    const float* mel    = (const float*)d_in[0];
    const float* pe     = (const float*)d_in[1];
    const float* proj_w = (const float*)d_in[2];
    const float* proj_b = (const float*)d_in[3];
    const float* Wq     = (const float*)d_in[4];
    const float* bq     = (const float*)d_in[5];
    const float* Wk     = (const float*)d_in[6];
    const float* bk     = (const float*)d_in[7];
    const float* Wv     = (const float*)d_in[8];
    const float* bv     = (const float*)d_in[9];
    const float* Wo     = (const float*)d_in[10];
    const float* bo     = (const float*)d_in[11];
    const float* ln1_g  = (const float*)d_in[12];
    const float* ln1_b  = (const float*)d_in[13];
    const float* ln2_g  = (const float*)d_in[14];
    const float* ln2_b  = (const float*)d_in[15];
    const float* Wi     = (const float*)d_in[16];
    const float* bi     = (const float*)d_in[17];
    const float* Wf     = (const float*)d_in[18];
    const float* bf     = (const float*)d_in[19];
    const float* lnf_g  = (const float*)d_in[20];
    const float* lnf_b  = (const float*)d_in[21];
    const float* lang_w = (const float*)d_in[22];
    const float* lang_b = (const float*)d_in[23];
    const float* int_w  = (const float*)d_in[24];
    const float* int_b  = (const float*)d_in[25];
    const float* emo_w  = (const float*)d_in[26];
    const float* emo_b  = (const float*)d_in[27];
    const float* sp_w   = (const float*)d_in[28];
    const float* sp_b   = (const float*)d_in[29];

    float* out = (float*)d_out;
    char* wsb = (char*)d_ws;

    const size_t MB = 1ull << 20;
    float* hbuf           = (float*)(wsb);                    // 0..16 MB residual f32
    __hip_bfloat16* xb    = (__hip_bfloat16*)(wsb + 16 * MB); // 16..24 LN out bf16
    __hip_bfloat16* qbuf  = (__hip_bfloat16*)(wsb + 24 * MB); // 24..32
    __hip_bfloat16* kbuf  = (__hip_bfloat16*)(wsb + 32 * MB); // 32..40
    __hip_bfloat16* vtb   = (__hip_bfloat16*)(wsb + 40 * MB); // 40..48
    __hip_bfloat16* ctx   = (__hip_bfloat16*)(wsb + 48 * MB); // 48..56
    __hip_bfloat16* gbuf  = (__hip_bfloat16*)(wsb + 24 * MB); // 24..56 (overlaps q/k/v/ctx)
    float* pooled         = (float*)(wsb + 56 * MB);          // 16 KB
    __hip_bfloat16* wqkv  = (__hip_bfloat16*)(wsb + 57 * MB); // 57..69.6: [L][1536][512]
    __hip_bfloat16* wot   = (__hip_bfloat16*)(wsb + 70 * MB); // 70..74
    __hip_bfloat16* wit   = (__hip_bfloat16*)(wsb + 74 * MB); // 74..90
    __hip_bfloat16* wft   = (__hip_bfloat16*)(wsb + 90 * MB); // 90..106
    __hip_bfloat16* spt   = (__hip_bfloat16*)(wsb + 107 * MB); // 107..108 (clear of wft)
    // total 108 MB

    // ---- weight conversion ----
    wconv_kernel<<<dim3(16, 16, LL), 256, 0, stream>>>(Wq, wqkv, DD, DD, 1536, 0);
    wconv_kernel<<<dim3(16, 16, LL), 256, 0, stream>>>(Wk, wqkv, DD, DD, 1536, 512);
    wconv_kernel<<<dim3(16, 16, LL), 256, 0, stream>>>(Wv, wqkv, DD, DD, 1536, 1024);
    wconv_kernel<<<dim3(16, 16, LL), 256, 0, stream>>>(Wo, wot, DD, DD, DD, 0);
    wconv_kernel<<<dim3(64, 16, LL), 256, 0, stream>>>(Wi, wit, DD, FF, FF, 0);
    wconv_kernel<<<dim3(16, 64, LL), 256, 0, stream>>>(Wf, wft, FF, DD, DD, 0);
    wconv_kernel<<<dim3(32, 16, 1),  256, 0, stream>>>(sp_w, spt, DD, 1000, 1024, 0);

    proj_pe_kernel<<<MM, 256, 0, stream>>>(mel, proj_w, proj_b, pe, hbuf);

    dim3 g512(4, 64);

    for (int l = 0; l < LL; ++l) {
        const __hip_bfloat16* wqkv_l = wqkv + (size_t)l * 1536 * DD;
        const __hip_bfloat16* wot_l  = wot  + (size_t)l * DD * DD;
        const __hip_bfloat16* wit_l  = wit  + (size_t)l * FF * DD;
        const __hip_bfloat16* wft_l  = wft  + (size_t)l * DD * FF;

        ln_kernel<<<MM, 256, 0, stream>>>(hbuf, ln1_g + l * DD, ln1_b + l * DD, xb);

        gemm_bf16<2, false, false><<<dim3(12, 64), 512, 0, stream>>>(
            xb, wqkv_l, bq + l * DD, bk + l * DD, bv + l * DD,
            nullptr, nullptr, qbuf, kbuf, vtb, MM, 1536, DD);

        attn_mfma<<<dim3(SS / 128, BB * HH), 512, 0, stream>>>(qbuf, kbuf, vtb, ctx);

        gemm_bf16<0, false, true><<<g512, 512, 0, stream>>>(
            ctx, wot_l, bo + l * DD, nullptr, nullptr,
            hbuf, hbuf, nullptr, nullptr, nullptr, MM, DD, DD);

        ln_kernel<<<MM, 256, 0, stream>>>(hbuf, ln2_g + l * DD, ln2_b + l * DD, xb);

        gemm_bf16<1, true, false><<<dim3(16, 64), 512, 0, stream>>>(
            xb, wit_l, bi + l * FF, nullptr, nullptr,
            nullptr, nullptr, gbuf, nullptr, nullptr, MM, FF, DD);
        gemm_bf16<0, false, true><<<g512, 512, 0, stream>>>(
            gbuf, wft_l, bf + l * DD, nullptr, nullptr,
            hbuf, hbuf, nullptr, nullptr, nullptr, MM, DD, FF);
    }

    ln_kernel<<<MM, 256, 0, stream>>>(hbuf, lnf_g, lnf_b, xb);
    pool_kernel<<<BB, 512, 0, stream>>>(xb, pooled);
    heads_kernel<<<BB, 256, 0, stream>>>(pooled, lang_w, lang_b, int_w, int_b,
                                         emo_w, emo_b, out);

    gemm_bf16<0, false, false><<<dim3(8, 64), 512, 0, stream>>>(
        xb, spt, sp_b, nullptr, nullptr,
        nullptr, out + 1264, nullptr, nullptr, nullptr, MM, 1000, DD);
}